// Round 1
// 710.143 us; speedup vs baseline: 1.0212x; 1.0212x over previous
//
#include <hip/hip_runtime.h>
#include <cstdint>
#include <cstddef>

// Problem constants
//   fine   [16,128,256,256]  coarse [16,7,64,64]
//   w1 [135,256] b1[256] w2 [256,7] b2[7]
//   over_gen [16,7168,2]  coverage [16,256,2]
//   out = rend [16,7,1024] (114688 floats) then points [16,1024,2] (32768 floats)
#define PTS_OFF 114688

// ---------------------------------------------------------------------------
// Kernel A: per batch — uncertainty of 7168 points, exact top-768 selection
// (value desc, ties by index asc == jax.lax.top_k), write points to d_out.
// One 1024-thread block per batch (16 blocks).
// Radix-select now runs on the 32-bit VALUE only (4 passes instead of 6):
// compact keeps every key with desc <= threshold (ties included, <=1024 of
// them with overwhelming probability); the 45-bit bitonic sort then orders
// value-desc / index-asc and the emit takes the first 768 — identical result
// to the previous exact-rank 6-pass version.
// Histogram is split into 4 per-wave-group sub-histograms: uncertainty floats
// cluster into ~3 exponent bytes, so a single 256-bin histogram serializes
// ~7168 LDS atomics onto ~3 addresses; the 4-way split cuts that 4x.
// ---------------------------------------------------------------------------
__global__ __launch_bounds__(1024) void select_points_kernel(
    const float* __restrict__ coarse,
    const float* __restrict__ over_gen,
    const float* __restrict__ coverage,
    float* out)
{
  const int b   = blockIdx.x;
  const int tid = threadIdx.x;

  __shared__ float sT1[4096];
  __shared__ float sT2[4096];
  __shared__ unsigned long long cand[1024];
  __shared__ unsigned int hist[1024];   // 4 sub-histograms x 256 bins
  __shared__ int sSel;
  __shared__ int sRnew;
  __shared__ unsigned int sCnt;

  // ---- phase 1: per-pixel top-2 of the 7 coarse channels -> LDS
  const float* cb = coarse + (size_t)b * 28672;
  for (int pix = tid; pix < 4096; pix += 1024) {
    float m1 = -INFINITY, m2 = -INFINITY;
#pragma unroll
    for (int ch = 0; ch < 7; ++ch) {
      float v = cb[ch * 4096 + pix];
      if (v > m1) { m2 = m1; m1 = v; }
      else if (v > m2) { m2 = v; }
    }
    sT1[pix] = m1;
    sT2[pix] = m2;
  }
  if (tid == 0) sCnt = 0u;
  __syncthreads();

  // ---- phase 2: uncertainty keys (exact f32 per-op rounding, no FMA)
  unsigned long long key[7];
  const float* og = over_gen + (size_t)b * 14336;
#pragma unroll
  for (int s = 0; s < 7; ++s) {
    int i = tid + s * 1024;
    float px = og[i * 2];
    float py = og[i * 2 + 1];
    float gx = __fsub_rn(__fmul_rn(2.0f, px), 1.0f);
    float gy = __fsub_rn(__fmul_rn(2.0f, py), 1.0f);
    float x  = __fmul_rn(__fsub_rn(__fmul_rn(__fadd_rn(gx, 1.0f), 64.0f), 1.0f), 0.5f);
    float y  = __fmul_rn(__fsub_rn(__fmul_rn(__fadd_rn(gy, 1.0f), 64.0f), 1.0f), 0.5f);
    float x0 = floorf(x), y0 = floorf(y);
    float wx = __fsub_rn(x, x0), wy = __fsub_rn(y, y0);
    float omwx = __fsub_rn(1.0f, wx), omwy = __fsub_rn(1.0f, wy);
    float x1 = x0 + 1.0f, y1 = y0 + 1.0f;

    float cxs[4] = {x0, x1, x0, x1};
    float cys[4] = {y0, y0, y1, y1};
    float t1[4], t2[4];
#pragma unroll
    for (int c = 0; c < 4; ++c) {
      bool valid = (cxs[c] >= 0.0f) && (cxs[c] <= 63.0f) &&
                   (cys[c] >= 0.0f) && (cys[c] <= 63.0f);
      int xi = (int)fminf(fmaxf(cxs[c], 0.0f), 63.0f);
      int yi = (int)fminf(fmaxf(cys[c], 0.0f), 63.0f);
      float m = valid ? 1.0f : 0.0f;
      int p = yi * 64 + xi;
      t1[c] = __fmul_rn(sT1[p], m);
      t2[c] = __fmul_rn(sT2[p], m);
    }
    float s0 = __fadd_rn(__fadd_rn(__fadd_rn(
        __fmul_rn(__fmul_rn(t1[0], omwx), omwy),
        __fmul_rn(__fmul_rn(t1[1], wx),   omwy)),
        __fmul_rn(__fmul_rn(t1[2], omwx), wy)),
        __fmul_rn(__fmul_rn(t1[3], wx),   wy));
    float s1 = __fadd_rn(__fadd_rn(__fadd_rn(
        __fmul_rn(__fmul_rn(t2[0], omwx), omwy),
        __fmul_rn(__fmul_rn(t2[1], wx),   omwy)),
        __fmul_rn(__fmul_rn(t2[2], omwx), wy)),
        __fmul_rn(__fmul_rn(t2[3], wx),   wy));
    float u = -__fsub_rn(s0, s1);
    unsigned int bits = __float_as_uint(u);
    unsigned int asc  = (bits & 0x80000000u) ? ~bits : (bits | 0x80000000u);
    unsigned int desc = ~asc;  // ascending in desc => descending value
    key[s] = ((unsigned long long)desc << 13) | (unsigned int)i;  // 45-bit key
  }

  // ---- radix-select the rank-768 VALUE (32-bit desc), 4 passes
  unsigned int P = 0u;
  unsigned int r = 768u;
  const int sub = ((tid >> 6) & 3) << 8;   // 4-way split histogram
  for (int pos = 3; pos >= 0; --pos) {
    const int shift = pos * 8;
    hist[tid] = 0u;
    __syncthreads();
#pragma unroll
    for (int s = 0; s < 7; ++s) {
      unsigned int d = (unsigned int)(key[s] >> 13);
      if ((((d ^ P) >> shift) >> 8) == 0u) {  // high bytes match prefix
        atomicAdd(&hist[sub | ((d >> shift) & 255u)], 1u);
      }
    }
    __syncthreads();
    // wave-0 scan of merged hist[256]: 4 bins/lane serial + shfl_up wave scan
    if (tid < 64) {
      unsigned int v0 = hist[tid*4]   + hist[256+tid*4]   + hist[512+tid*4]   + hist[768+tid*4];
      unsigned int v1 = hist[tid*4+1] + hist[256+tid*4+1] + hist[512+tid*4+1] + hist[768+tid*4+1];
      unsigned int v2 = hist[tid*4+2] + hist[256+tid*4+2] + hist[512+tid*4+2] + hist[768+tid*4+2];
      unsigned int v3 = hist[tid*4+3] + hist[256+tid*4+3] + hist[512+tid*4+3] + hist[768+tid*4+3];
      v1 += v0; v2 += v1; v3 += v2;
      unsigned int lanesum = v3;
      unsigned int inc = lanesum;
#pragma unroll
      for (int d = 1; d < 64; d <<= 1) {
        unsigned int tsum = __shfl_up(inc, d, 64);
        if (tid >= d) inc += tsum;
      }
      unsigned int excl = inc - lanesum;
      v0 += excl; v1 += excl; v2 += excl; v3 += excl;
      if (excl < r && r <= v0) { sSel = tid * 4;     sRnew = (int)(r - excl); }
      if (v0   < r && r <= v1) { sSel = tid * 4 + 1; sRnew = (int)(r - v0);   }
      if (v1   < r && r <= v2) { sSel = tid * 4 + 2; sRnew = (int)(r - v1);   }
      if (v2   < r && r <= v3) { sSel = tid * 4 + 3; sRnew = (int)(r - v2);   }
    }
    __syncthreads();
    P |= ((unsigned int)sSel) << shift;
    r = (unsigned int)sRnew;
  }

  // ---- compact all keys with value >= threshold value (desc <= P).
  // Count is 768 + (#ties at threshold) <= 1024 in practice; the sort below
  // orders them exactly and emit takes the first 768.
  cand[tid] = 0xFFFFFFFFFFFFFFFFull;
  __syncthreads();
#pragma unroll
  for (int s = 0; s < 7; ++s) {
    if ((unsigned int)(key[s] >> 13) <= P) {
      unsigned int p = atomicAdd(&sCnt, 1u);
      if (p < 1024u) cand[p] = key[s];
    }
  }
  __syncthreads();

  // ---- bitonic sort 1024, shuffle-assisted (j<=32 in registers)
  {
    unsigned long long e = cand[tid];
    // kk = 2..64: entire merge in-wave (all j <= 32), zero barriers
#pragma unroll
    for (int kk = 2; kk <= 64; kk <<= 1) {
      for (int j = kk >> 1; j >= 1; j >>= 1) {
        unsigned long long p = __shfl_xor(e, j, 64);
        bool up    = ((tid & kk) == 0);
        bool lower = ((tid & j) == 0);
        bool takemin = (lower == up);
        unsigned long long mn = (e < p) ? e : p;
        unsigned long long mx = (e < p) ? p : e;
        e = takemin ? mn : mx;
      }
    }
    cand[tid] = e;
    __syncthreads();

    for (int kk = 128; kk <= 1024; kk <<= 1) {
      // LDS phases for j >= 64 (cross-wave partners)
      for (int j = kk >> 1; j >= 64; j >>= 1) {
        int ixj = tid ^ j;
        if (ixj > tid) {
          unsigned long long a = cand[tid];
          unsigned long long c = cand[ixj];
          bool up = ((tid & kk) == 0);
          if ((a > c) == up) { cand[tid] = c; cand[ixj] = a; }
        }
        __syncthreads();
      }
      // register phases j = 32..1 (in-wave)
      e = cand[tid];
      bool up = ((tid & kk) == 0);
#pragma unroll
      for (int j = 32; j >= 1; j >>= 1) {
        unsigned long long p = __shfl_xor(e, j, 64);
        bool lower = ((tid & j) == 0);
        bool takemin = (lower == up);
        unsigned long long mn = (e < p) ? e : p;
        unsigned long long mx = (e < p) ? p : e;
        e = takemin ? mn : mx;
      }
      cand[tid] = e;
      __syncthreads();
    }
  }

  // ---- emit points: 768 importance + 256 coverage
  float* po = out + PTS_OFF + (size_t)b * 2048;
  if (tid < 768) {
    unsigned int idx = (unsigned int)(cand[tid] & 0x1FFFu);
    po[tid * 2]     = og[idx * 2];
    po[tid * 2 + 1] = og[idx * 2 + 1];
  } else {
    int j = tid - 768;
    po[tid * 2]     = coverage[(size_t)b * 512 + j * 2];
    po[tid * 2 + 1] = coverage[(size_t)b * 512 + j * 2 + 1];
  }
}

// ---------------------------------------------------------------------------
// Kernel B: bilinear gather (7 coarse + 128 fine ch) + MLP 135->256->7.
// Block = 256 threads handles 16 points (1024 blocks total, 2x the waves/CU
// of the previous 512-block version: the random fine-gather is HBM-latency
// bound, so doubling resident waves doubles outstanding misses).
// GATHER: thread t -> point (t&15), channels (t>>4)*8 .. +7.  A wave's 64
//   lanes hit 4 channel planes at 16 random offsets each.
// COMPUTE: wave handles 4 points; lane owns neurons lane+64r; shuffle-reduce
//   layer 2 across the wave.  Per-point arithmetic identical to the previous
//   version (same fmaf chains, same reduction order) -> bit-identical output.
// ---------------------------------------------------------------------------
__global__ __launch_bounds__(256) void point_head_kernel(
    const float* __restrict__ fine,
    const float* __restrict__ coarse,
    const float* __restrict__ gw1,
    const float* __restrict__ gb1,
    const float* __restrict__ gw2,
    const float* __restrict__ gb2,
    float* out)
{
  const int t   = threadIdx.x;
  const int blk = blockIdx.x;        // 0..1023
  const int b   = blk >> 6;          // 64 blocks per batch
  const int n0  = (blk & 63) * 16;   // first point of this block

  __shared__ float sFeat[16][137];   // stride 137: LDS-bank conflict free

  const float* pts = out + PTS_OFF + (size_t)b * 2048;
  const float* fb  = fine   + (size_t)b * 8388608;  // 128*65536
  const float* cbs = coarse + (size_t)b * 28672;    // 7*4096

  // ---- gather phase ----
  {
    const int pt = t & 15;
    const int cg = t >> 4;           // 0..15 -> 8 fine channels each
    float px = pts[(n0 + pt) * 2];
    float py = pts[(n0 + pt) * 2 + 1];

    // fine grid (256x256) bilinear setup
    float gx = 2.0f * px - 1.0f;
    float gy = 2.0f * py - 1.0f;
    float x  = ((gx + 1.0f) * 256.0f - 1.0f) * 0.5f;
    float y  = ((gy + 1.0f) * 256.0f - 1.0f) * 0.5f;
    float x0f = floorf(x), y0f = floorf(y);
    float wx = x - x0f, wy = y - y0f;
    int ix0 = (int)x0f, iy0 = (int)y0f;
    int ix1 = ix0 + 1,  iy1 = iy0 + 1;
    float mx0 = (ix0 >= 0 && ix0 <= 255) ? 1.0f : 0.0f;
    float mx1 = (ix1 >= 0 && ix1 <= 255) ? 1.0f : 0.0f;
    float my0 = (iy0 >= 0 && iy0 <= 255) ? 1.0f : 0.0f;
    float my1 = (iy1 >= 0 && iy1 <= 255) ? 1.0f : 0.0f;
    int cx0 = min(max(ix0, 0), 255), cx1 = min(max(ix1, 0), 255);
    int cy0 = min(max(iy0, 0), 255), cy1 = min(max(iy1, 0), 255);
    float W00 = (1.0f - wx) * (1.0f - wy) * mx0 * my0;
    float W01 = wx * (1.0f - wy) * mx1 * my0;
    float W10 = (1.0f - wx) * wy * mx0 * my1;
    float W11 = wx * wy * mx1 * my1;
    int o00 = cy0 * 256 + cx0, o01 = cy0 * 256 + cx1;
    int o10 = cy1 * 256 + cx0, o11 = cy1 * 256 + cx1;

#pragma unroll
    for (int i = 0; i < 8; ++i) {
      int ch = cg * 8 + i;
      const float* f = fb + (size_t)ch * 65536;
      sFeat[pt][7 + ch] = f[o00] * W00 + f[o01] * W01 + f[o10] * W10 + f[o11] * W11;
    }

    // coarse grid (64x64): cg==0 threads handle all 7 channels of their point
    if (cg == 0) {
      float cx  = ((gx + 1.0f) * 64.0f - 1.0f) * 0.5f;
      float cy  = ((gy + 1.0f) * 64.0f - 1.0f) * 0.5f;
      float cx0f = floorf(cx), cy0f = floorf(cy);
      float cwx = cx - cx0f, cwy = cy - cy0f;
      int jx0 = (int)cx0f, jy0 = (int)cy0f;
      int jx1 = jx0 + 1,   jy1 = jy0 + 1;
      float nx0 = (jx0 >= 0 && jx0 <= 63) ? 1.0f : 0.0f;
      float nx1 = (jx1 >= 0 && jx1 <= 63) ? 1.0f : 0.0f;
      float ny0 = (jy0 >= 0 && jy0 <= 63) ? 1.0f : 0.0f;
      float ny1 = (jy1 >= 0 && jy1 <= 63) ? 1.0f : 0.0f;
      int kx0 = min(max(jx0, 0), 63), kx1 = min(max(jx1, 0), 63);
      int ky0 = min(max(jy0, 0), 63), ky1 = min(max(jy1, 0), 63);
      float V00 = (1.0f - cwx) * (1.0f - cwy) * nx0 * ny0;
      float V01 = cwx * (1.0f - cwy) * nx1 * ny0;
      float V10 = (1.0f - cwx) * cwy * nx0 * ny1;
      float V11 = cwx * cwy * nx1 * ny1;
      int q00 = ky0 * 64 + kx0, q01 = ky0 * 64 + kx1;
      int q10 = ky1 * 64 + kx0, q11 = ky1 * 64 + kx1;
#pragma unroll
      for (int ch = 0; ch < 7; ++ch) {
        const float* c0 = cbs + ch * 4096;
        sFeat[pt][ch] = c0[q00] * V00 + c0[q01] * V01 + c0[q10] * V10 + c0[q11] * V11;
      }
    }
  }
  __syncthreads();

  // ---- layer 1: h[256] = relu(feat @ w1 + b1); wave wid owns 4 points
  const int lane = t & 63;
  const int wid  = t >> 6;
  const int p0   = wid * 4;

  float acc[4][4];
  {
    float bb0 = gb1[lane], bb1 = gb1[lane + 64];
    float bb2 = gb1[lane + 128], bb3 = gb1[lane + 192];
#pragma unroll
    for (int p = 0; p < 4; ++p) {
      acc[p][0] = bb0; acc[p][1] = bb1; acc[p][2] = bb2; acc[p][3] = bb3;
    }
  }
  for (int c = 0; c < 135; ++c) {
    const float* wr = gw1 + c * 256;
    float wv0 = wr[lane], wv1 = wr[lane + 64];
    float wv2 = wr[lane + 128], wv3 = wr[lane + 192];
#pragma unroll
    for (int p = 0; p < 4; ++p) {
      float fv = sFeat[p0 + p][c];   // broadcast read, conflict-free
      acc[p][0] = fmaf(fv, wv0, acc[p][0]);
      acc[p][1] = fmaf(fv, wv1, acc[p][1]);
      acc[p][2] = fmaf(fv, wv2, acc[p][2]);
      acc[p][3] = fmaf(fv, wv3, acc[p][3]);
    }
  }

  // ---- layer 2: rend[7] = relu(h) @ w2 + b2, wave-reduced via shuffles
  float w2v[4][7];
#pragma unroll
  for (int rr = 0; rr < 4; ++rr) {
    const float* wr = gw2 + (size_t)(lane + 64 * rr) * 7;
#pragma unroll
    for (int k = 0; k < 7; ++k) w2v[rr][k] = wr[k];
  }
  float b2s = (lane < 7) ? gb2[lane] : 0.0f;

#pragma unroll
  for (int p = 0; p < 4; ++p) {
    float part[7];
#pragma unroll
    for (int k = 0; k < 7; ++k) part[k] = 0.0f;
#pragma unroll
    for (int rr = 0; rr < 4; ++rr) {
      float h = fmaxf(acc[p][rr], 0.0f);
#pragma unroll
      for (int k = 0; k < 7; ++k) part[k] = fmaf(h, w2v[rr][k], part[k]);
    }
#pragma unroll
    for (int k = 0; k < 7; ++k) {
      float s = part[k];
#pragma unroll
      for (int off = 32; off > 0; off >>= 1) s += __shfl_xor(s, off, 64);
      if (lane == k) out[((size_t)b * 7 + k) * 1024 + (n0 + p0 + p)] = s + b2s;
    }
  }
}

extern "C" void kernel_launch(void* const* d_in, const int* in_sizes, int n_in,
                              void* d_out, int out_size, void* d_ws, size_t ws_size,
                              hipStream_t stream) {
  (void)in_sizes; (void)n_in; (void)d_ws; (void)ws_size; (void)out_size;
  const float* fine     = (const float*)d_in[0];
  const float* coarse   = (const float*)d_in[1];
  const float* w1       = (const float*)d_in[2];
  const float* b1       = (const float*)d_in[3];
  const float* w2       = (const float*)d_in[4];
  const float* b2       = (const float*)d_in[5];
  const float* over_gen = (const float*)d_in[6];
  const float* coverage = (const float*)d_in[7];
  float* out = (float*)d_out;

  select_points_kernel<<<16, 1024, 0, stream>>>(coarse, over_gen, coverage, out);
  point_head_kernel<<<1024, 256, 0, stream>>>(fine, coarse, w1, b1, w2, b2, out);
}